// Round 1
// baseline (309.340 us; speedup 1.0000x reference)
//
#include <hip/hip_runtime.h>
#include <hip/hip_bf16.h>
#include <stdint.h>

#define M_BATCH 1024
#define N_OUT   4096
#define K_IN    4096

#define BM 128
#define BN 128
#define BK 64

typedef __attribute__((ext_vector_type(8))) __bf16 bf16x8_t;
typedef __attribute__((ext_vector_type(4))) float f32x4_t;

__device__ __forceinline__ unsigned short f2bf_bits(float f) {
    union { __hip_bfloat16 h; unsigned short u; } cvt;
    cvt.h = __float2bfloat16(f);  // RNE
    return cvt.u;
}

struct __align__(8) US4 { unsigned short x, y, z, w; };

// Kernel 1: w_bf16 = bf16(mu + eps*sigma); x_bf16 = bf16(x). Pure HBM-bound.
__global__ __launch_bounds__(256) void prep_kernel(
    const float* __restrict__ x,
    const float* __restrict__ wmu,
    const float* __restrict__ wsig,
    const float* __restrict__ epsw,
    unsigned short* __restrict__ wb,
    unsigned short* __restrict__ xb)
{
    const size_t tid    = (size_t)blockIdx.x * blockDim.x + threadIdx.x;
    const size_t stride = (size_t)gridDim.x * blockDim.x;

    const size_t NW4 = (size_t)N_OUT * K_IN / 4;
    const float4* wmu4  = (const float4*)wmu;
    const float4* wsig4 = (const float4*)wsig;
    const float4* epsw4 = (const float4*)epsw;
    US4* wb4 = (US4*)wb;
    for (size_t i = tid; i < NW4; i += stride) {
        float4 m = wmu4[i], s = wsig4[i], e = epsw4[i];
        US4 o;
        o.x = f2bf_bits(fmaf(e.x, s.x, m.x));
        o.y = f2bf_bits(fmaf(e.y, s.y, m.y));
        o.z = f2bf_bits(fmaf(e.z, s.z, m.z));
        o.w = f2bf_bits(fmaf(e.w, s.w, m.w));
        wb4[i] = o;
    }

    const size_t NX4 = (size_t)M_BATCH * K_IN / 4;
    const float4* x4 = (const float4*)x;
    US4* xb4 = (US4*)xb;
    for (size_t i = tid; i < NX4; i += stride) {
        float4 v = x4[i];
        US4 o;
        o.x = f2bf_bits(v.x);
        o.y = f2bf_bits(v.y);
        o.z = f2bf_bits(v.z);
        o.w = f2bf_bits(v.w);
        xb4[i] = o;
    }
}

// Kernel 2: C = A @ B^T + bias.  A=[M][K] bf16, B=[N][K] bf16 (row-major, dot
// along K — the verified gemm_bt layout). m97 structure: 128x128 tile, BK=64,
// global_load_lds width=16, 16x16x32 bf16 MFMA. 512 threads = 8 waves, each
// wave owns a 64x32 sub-tile (acc[4][2]).
__global__ __launch_bounds__(512, 2) void gemm_bt_kernel(
    const unsigned short* __restrict__ A,
    const unsigned short* __restrict__ B,
    const float* __restrict__ bmu,
    const float* __restrict__ bsig,
    const float* __restrict__ ebias,
    float* __restrict__ C)
{
    __shared__ unsigned short As[BM * BK];  // [BM][BK] row-major, 16 KiB
    __shared__ unsigned short Bs[BN * BK];  // [BN][BK] row-major, 16 KiB

    const int t    = threadIdx.x;
    const int bm0  = blockIdx.y * BM;
    const int bn0  = blockIdx.x * BN;
    const int lane = t & 63;
    const int wave = t >> 6;
    const int wm   = (wave >> 2) * 64;   // wave row origin   (0 / 64)
    const int wn   = (wave & 3) * 32;    // wave col origin   (0/32/64/96)
    const int lm   = lane & 15;
    const int quad = lane >> 4;

    f32x4_t acc[4][2] = {};

    // Staging map: thread t moves the t-th 16B chunk of each 64-row half-tile.
    // LDS byte offset = t*16  ->  row = t>>3, col8 = (t&7)*8 elements.
    // Wave-uniform base + lane*16 holds (global_load_lds constraint).
    const int srow = t >> 3;        // 0..63
    const int scol = (t & 7) * 8;   // element col
    const unsigned short* ag = A + (size_t)(bm0 + srow) * K_IN + scol;
    const unsigned short* bg = B + (size_t)(bn0 + srow) * K_IN + scol;
    char* asDst = (char*)As + t * 16;
    char* bsDst = (char*)Bs + t * 16;

    for (int k0 = 0; k0 < K_IN; k0 += BK) {
        __builtin_amdgcn_global_load_lds(
            (const __attribute__((address_space(1))) void*)(ag + k0),
            (__attribute__((address_space(3))) void*)asDst, 16, 0, 0);
        __builtin_amdgcn_global_load_lds(
            (const __attribute__((address_space(1))) void*)(ag + k0 + (size_t)64 * K_IN),
            (__attribute__((address_space(3))) void*)(asDst + 8192), 16, 0, 0);
        __builtin_amdgcn_global_load_lds(
            (const __attribute__((address_space(1))) void*)(bg + k0),
            (__attribute__((address_space(3))) void*)bsDst, 16, 0, 0);
        __builtin_amdgcn_global_load_lds(
            (const __attribute__((address_space(1))) void*)(bg + k0 + (size_t)64 * K_IN),
            (__attribute__((address_space(3))) void*)(bsDst + 8192), 16, 0, 0);
        __syncthreads();  // drains vmcnt -> LDS tiles visible

        #pragma unroll
        for (int kk = 0; kk < BK; kk += 32) {
            bf16x8_t a_frag[4], b_frag[2];
            #pragma unroll
            for (int im = 0; im < 4; im++) {
                const unsigned short* p = As + (wm + im * 16 + lm) * BK + kk + quad * 8;
                a_frag[im] = *(const bf16x8_t*)p;  // ds_read_b128
            }
            #pragma unroll
            for (int jn = 0; jn < 2; jn++) {
                const unsigned short* p = Bs + (wn + jn * 16 + lm) * BK + kk + quad * 8;
                b_frag[jn] = *(const bf16x8_t*)p;
            }
            #pragma unroll
            for (int im = 0; im < 4; im++)
                #pragma unroll
                for (int jn = 0; jn < 2; jn++)
                    acc[im][jn] = __builtin_amdgcn_mfma_f32_16x16x32_bf16(
                        a_frag[im], b_frag[jn], acc[im][jn], 0, 0, 0);
        }
        __syncthreads();  // all LDS reads done before next stage overwrites
    }

    // Epilogue: C/D layout col=lane&15, row=quad*4+reg (m89-verified). Fuse bias.
    #pragma unroll
    for (int jn = 0; jn < 2; jn++) {
        const int gn = bn0 + wn + jn * 16 + lm;
        const float bias = bmu[gn] + ebias[gn] * bsig[gn];
        #pragma unroll
        for (int im = 0; im < 4; im++) {
            const int gm0 = bm0 + wm + im * 16 + quad * 4;
            #pragma unroll
            for (int r = 0; r < 4; r++)
                C[(size_t)(gm0 + r) * N_OUT + gn] = acc[im][jn][r] + bias;
        }
    }
}

// Insurance path if d_ws is too small for the bf16 staging buffers.
__global__ __launch_bounds__(256) void naive_kernel(
    const float* __restrict__ x, const float* __restrict__ wmu,
    const float* __restrict__ wsig, const float* __restrict__ bmu,
    const float* __restrict__ bsig, const float* __restrict__ epsw,
    const float* __restrict__ epsb, float* __restrict__ out)
{
    const int o = blockIdx.x * blockDim.x + threadIdx.x;
    const int b = blockIdx.y;
    const float4* xr = (const float4*)(x + (size_t)b * K_IN);
    const float4* mr = (const float4*)(wmu + (size_t)o * K_IN);
    const float4* sr = (const float4*)(wsig + (size_t)o * K_IN);
    const float4* er = (const float4*)(epsw + (size_t)o * K_IN);
    float s = 0.f;
    for (int k = 0; k < K_IN / 4; k++) {
        float4 xv = xr[k], m = mr[k], sg = sr[k], e = er[k];
        s += xv.x * fmaf(e.x, sg.x, m.x);
        s += xv.y * fmaf(e.y, sg.y, m.y);
        s += xv.z * fmaf(e.z, sg.z, m.z);
        s += xv.w * fmaf(e.w, sg.w, m.w);
    }
    out[(size_t)b * N_OUT + o] = s + bmu[o] + epsb[o] * bsig[o];
}

extern "C" void kernel_launch(void* const* d_in, const int* in_sizes, int n_in,
                              void* d_out, int out_size, void* d_ws, size_t ws_size,
                              hipStream_t stream)
{
    const float* x    = (const float*)d_in[0];
    const float* wmu  = (const float*)d_in[1];
    const float* wsig = (const float*)d_in[2];
    const float* bmu  = (const float*)d_in[3];
    const float* bsig = (const float*)d_in[4];
    const float* epsw = (const float*)d_in[5];
    const float* epsb = (const float*)d_in[6];
    float* out = (float*)d_out;

    const size_t need = ((size_t)N_OUT * K_IN + (size_t)M_BATCH * K_IN) * sizeof(unsigned short);
    if (ws_size >= need) {
        unsigned short* wb = (unsigned short*)d_ws;                  // [N][K] bf16
        unsigned short* xb = wb + (size_t)N_OUT * K_IN;              // [M][K] bf16
        prep_kernel<<<2048, 256, 0, stream>>>(x, wmu, wsig, epsw, wb, xb);
        dim3 grid(N_OUT / BN, M_BATCH / BM);                         // 32 x 8 = 256 blocks
        gemm_bt_kernel<<<grid, 512, 0, stream>>>(xb, wb, bmu, bsig, epsb, out);
    } else {
        dim3 grid(N_OUT / 256, M_BATCH);
        naive_kernel<<<grid, 256, 0, stream>>>(x, wmu, wsig, bmu, bsig, epsw, epsb, out);
    }
}

// Round 2
// 281.086 us; speedup vs baseline: 1.1005x; 1.1005x over previous
//
#include <hip/hip_runtime.h>
#include <hip/hip_bf16.h>
#include <stdint.h>

#define M_BATCH 1024
#define N_OUT   4096
#define K_IN    4096

#define BM 128
#define BN 128
#define BK 64
#define KSPLIT 2
#define KPER  (K_IN / KSPLIT)   // 2048
#define KITER (KPER / BK)       // 32

typedef __attribute__((ext_vector_type(8))) __bf16 bf16x8_t;
typedef __attribute__((ext_vector_type(4))) float f32x4_t;

__device__ __forceinline__ unsigned short f2bf_bits(float f) {
    union { __hip_bfloat16 h; unsigned short u; } cvt;
    cvt.h = __float2bfloat16(f);  // RNE
    return cvt.u;
}

struct __align__(8) US4 { unsigned short x, y, z, w; };

// Kernel 1: w_bf16 = bf16(mu + eps*sigma); x_bf16 = bf16(x); zero C.
// Pure HBM-bound (~250 MB).
__global__ __launch_bounds__(256) void prep_kernel(
    const float* __restrict__ x,
    const float* __restrict__ wmu,
    const float* __restrict__ wsig,
    const float* __restrict__ epsw,
    unsigned short* __restrict__ wb,
    unsigned short* __restrict__ xb,
    float4* __restrict__ czero)
{
    const size_t tid    = (size_t)blockIdx.x * blockDim.x + threadIdx.x;
    const size_t stride = (size_t)gridDim.x * blockDim.x;

    const size_t NW4 = (size_t)N_OUT * K_IN / 4;
    const float4* wmu4  = (const float4*)wmu;
    const float4* wsig4 = (const float4*)wsig;
    const float4* epsw4 = (const float4*)epsw;
    US4* wb4 = (US4*)wb;
    for (size_t i = tid; i < NW4; i += stride) {
        float4 m = wmu4[i], s = wsig4[i], e = epsw4[i];
        US4 o;
        o.x = f2bf_bits(fmaf(e.x, s.x, m.x));
        o.y = f2bf_bits(fmaf(e.y, s.y, m.y));
        o.z = f2bf_bits(fmaf(e.z, s.z, m.z));
        o.w = f2bf_bits(fmaf(e.w, s.w, m.w));
        wb4[i] = o;
    }

    const size_t NX4 = (size_t)M_BATCH * K_IN / 4;
    const float4* x4 = (const float4*)x;
    US4* xb4 = (US4*)xb;
    for (size_t i = tid; i < NX4; i += stride) {
        float4 v = x4[i];
        US4 o;
        o.x = f2bf_bits(v.x);
        o.y = f2bf_bits(v.y);
        o.z = f2bf_bits(v.z);
        o.w = f2bf_bits(v.w);
        xb4[i] = o;
    }

    // Zero the output (gemm accumulates with atomicAdd under split-K).
    const size_t NC4 = (size_t)M_BATCH * N_OUT / 4;
    const float4 z = {0.f, 0.f, 0.f, 0.f};
    for (size_t i = tid; i < NC4; i += stride) czero[i] = z;
}

// Kernel 2: C += A @ B^T (+ bias on the ks==0 split).
// A=[M][K] bf16, B=[N][K] bf16. 128x128 tile, BK=64, split-K x2 (grid z),
// 256 threads = 4 waves, each wave a 64x64 sub-tile (acc[4][4], m97 shape).
// LDS XOR-swizzled (phys_chunk = logical_chunk ^ (row&7)) to kill the 16-way
// bank conflict of a 128-byte row stride; the swizzle is applied on the
// GLOBAL source address since global_load_lds forces contiguous LDS dst.
// Single barrier per K-iter; prefetch issued right after the barrier so the
// global->LDS DMA overlaps the ds_read+MFMA phase (double-buffered LDS).
__global__ __launch_bounds__(256, 2) void gemm_bt_kernel(
    const unsigned short* __restrict__ A,
    const unsigned short* __restrict__ B,
    const float* __restrict__ bmu,
    const float* __restrict__ bsig,
    const float* __restrict__ ebias,
    float* __restrict__ C)
{
    __shared__ unsigned short As[2 * BM * BK];  // 2 x 16 KiB
    __shared__ unsigned short Bs[2 * BN * BK];  // 2 x 16 KiB

    const int t     = threadIdx.x;
    const int bm0   = blockIdx.y * BM;
    const int bn0   = blockIdx.x * BN;
    const int kbase = blockIdx.z * KPER;
    const int lane  = t & 63;
    const int wave  = t >> 6;
    const int wrow  = (wave >> 1) * 64;
    const int wcol  = (wave & 1) * 64;
    const int lm    = lane & 15;
    const int quad  = lane >> 4;

    f32x4_t acc[4][4] = {};

    // Staging map: thread t stages the 16B chunk at LDS (row = s*32 + (t>>3),
    // phys_chunk = t&7). It must therefore FETCH logical chunk
    // jg = (t&7) ^ (row&7) of that row. (row&7) == ((t>>3)&7) since s*32 % 8 == 0.
    const int srow = t >> 3;                 // 0..31
    const int jg   = (t & 7) ^ (srow & 7);   // swizzled source chunk
    const unsigned short* ag = A + (size_t)(bm0 + srow) * K_IN + kbase + jg * 8;
    const unsigned short* bg = B + (size_t)(bn0 + srow) * K_IN + kbase + jg * 8;
    char* asDst = (char*)As + t * 16;
    char* bsDst = (char*)Bs + t * 16;

    // Stage tile 0 into buffer 0.
    #pragma unroll
    for (int s = 0; s < 4; ++s) {
        __builtin_amdgcn_global_load_lds(
            (const __attribute__((address_space(1))) void*)(ag + (size_t)s * 32 * K_IN),
            (__attribute__((address_space(3))) void*)(asDst + s * 4096), 16, 0, 0);
        __builtin_amdgcn_global_load_lds(
            (const __attribute__((address_space(1))) void*)(bg + (size_t)s * 32 * K_IN),
            (__attribute__((address_space(3))) void*)(bsDst + s * 4096), 16, 0, 0);
    }

    for (int it = 0; it < KITER; ++it) {
        __syncthreads();  // drains vmcnt: buf(it&1) ready; prior reads of the other buf done

        if (it + 1 < KITER) {
            const int koff = (it + 1) * BK;
            const int nb   = ((it + 1) & 1) * 16384;  // byte offset of next buffer
            #pragma unroll
            for (int s = 0; s < 4; ++s) {
                __builtin_amdgcn_global_load_lds(
                    (const __attribute__((address_space(1))) void*)(ag + (size_t)s * 32 * K_IN + koff),
                    (__attribute__((address_space(3))) void*)(asDst + nb + s * 4096), 16, 0, 0);
                __builtin_amdgcn_global_load_lds(
                    (const __attribute__((address_space(1))) void*)(bg + (size_t)s * 32 * K_IN + koff),
                    (__attribute__((address_space(3))) void*)(bsDst + nb + s * 4096), 16, 0, 0);
            }
        }

        const unsigned short* Ab = As + (it & 1) * 8192;
        const unsigned short* Bb = Bs + (it & 1) * 8192;

        #pragma unroll
        for (int kk = 0; kk < 2; ++kk) {  // two 16x16x32 K-steps per BK=64
            const int pbase = kk * 4;     // logical chunk base for this K-step
            bf16x8_t a_frag[4], b_frag[4];
            #pragma unroll
            for (int im = 0; im < 4; im++) {
                const int R = wrow + im * 16 + lm;
                const int p = (pbase + quad) ^ (lm & 7);   // de-swizzle
                a_frag[im] = *(const bf16x8_t*)(Ab + R * BK + p * 8);
            }
            #pragma unroll
            for (int jn = 0; jn < 4; jn++) {
                const int R = wcol + jn * 16 + lm;
                const int p = (pbase + quad) ^ (lm & 7);
                b_frag[jn] = *(const bf16x8_t*)(Bb + R * BK + p * 8);
            }
            #pragma unroll
            for (int im = 0; im < 4; im++)
                #pragma unroll
                for (int jn = 0; jn < 4; jn++)
                    acc[im][jn] = __builtin_amdgcn_mfma_f32_16x16x32_bf16(
                        a_frag[im], b_frag[jn], acc[im][jn], 0, 0, 0);
        }
    }

    // Epilogue: C/D layout col=lane&15, row=quad*4+r (m89-verified).
    // Split-K partials accumulate with device-scope atomics into zeroed C;
    // bias contributed only by the ks==0 split.
    #pragma unroll
    for (int jn = 0; jn < 4; jn++) {
        const int gn = bn0 + wcol + jn * 16 + lm;
        const float bias = (kbase == 0) ? (bmu[gn] + ebias[gn] * bsig[gn]) : 0.f;
        #pragma unroll
        for (int im = 0; im < 4; im++) {
            const int gm0 = bm0 + wrow + im * 16 + quad * 4;
            #pragma unroll
            for (int r = 0; r < 4; r++)
                atomicAdd(&C[(size_t)(gm0 + r) * N_OUT + gn], acc[im][jn][r] + bias);
        }
    }
}

// Insurance path if d_ws is too small for the bf16 staging buffers.
__global__ __launch_bounds__(256) void naive_kernel(
    const float* __restrict__ x, const float* __restrict__ wmu,
    const float* __restrict__ wsig, const float* __restrict__ bmu,
    const float* __restrict__ bsig, const float* __restrict__ epsw,
    const float* __restrict__ epsb, float* __restrict__ out)
{
    const int o = blockIdx.x * blockDim.x + threadIdx.x;
    const int b = blockIdx.y;
    const float4* xr = (const float4*)(x + (size_t)b * K_IN);
    const float4* mr = (const float4*)(wmu + (size_t)o * K_IN);
    const float4* sr = (const float4*)(wsig + (size_t)o * K_IN);
    const float4* er = (const float4*)(epsw + (size_t)o * K_IN);
    float s = 0.f;
    for (int k = 0; k < K_IN / 4; k++) {
        float4 xv = xr[k], m = mr[k], sg = sr[k], e = er[k];
        s += xv.x * fmaf(e.x, sg.x, m.x);
        s += xv.y * fmaf(e.y, sg.y, m.y);
        s += xv.z * fmaf(e.z, sg.z, m.z);
        s += xv.w * fmaf(e.w, sg.w, m.w);
    }
    out[(size_t)b * N_OUT + o] = s + bmu[o] + epsb[o] * bsig[o];
}

extern "C" void kernel_launch(void* const* d_in, const int* in_sizes, int n_in,
                              void* d_out, int out_size, void* d_ws, size_t ws_size,
                              hipStream_t stream)
{
    const float* x    = (const float*)d_in[0];
    const float* wmu  = (const float*)d_in[1];
    const float* wsig = (const float*)d_in[2];
    const float* bmu  = (const float*)d_in[3];
    const float* bsig = (const float*)d_in[4];
    const float* epsw = (const float*)d_in[5];
    const float* epsb = (const float*)d_in[6];
    float* out = (float*)d_out;

    const size_t need = ((size_t)N_OUT * K_IN + (size_t)M_BATCH * K_IN) * sizeof(unsigned short);
    if (ws_size >= need) {
        unsigned short* wb = (unsigned short*)d_ws;                  // [N][K] bf16
        unsigned short* xb = wb + (size_t)N_OUT * K_IN;              // [M][K] bf16
        prep_kernel<<<2048, 256, 0, stream>>>(x, wmu, wsig, epsw, wb, xb, (float4*)out);
        dim3 grid(N_OUT / BN, M_BATCH / BM, KSPLIT);                 // 32 x 8 x 2 = 512 blocks
        gemm_bt_kernel<<<grid, 256, 0, stream>>>(xb, wb, bmu, bsig, epsb, out);
    } else {
        dim3 grid(N_OUT / 256, M_BATCH);
        naive_kernel<<<grid, 256, 0, stream>>>(x, wmu, wsig, bmu, bsig, epsw, epsb, out);
    }
}

// Round 4
// 242.702 us; speedup vs baseline: 1.2746x; 1.1582x over previous
//
#include <hip/hip_runtime.h>
#include <hip/hip_bf16.h>
#include <stdint.h>

#define M_BATCH 1024
#define N_OUT   4096
#define K_IN    4096

#define BM 128
#define BN 128
#define BK 64
#define KPER  (K_IN / 2)        // 2048 per intra-block k-half
#define KITER (KPER / BK)       // 32

typedef __attribute__((ext_vector_type(8))) __bf16 bf16x8_t;
typedef __attribute__((ext_vector_type(4))) float f32x4_t;
typedef __attribute__((ext_vector_type(4))) float fvec4;   // clang vector: OK for nontemporal builtins

__device__ __forceinline__ unsigned short f2bf_bits(float f) {
    union { __hip_bfloat16 h; unsigned short u; } cvt;
    cvt.h = __float2bfloat16(f);  // RNE
    return cvt.u;
}

struct __align__(8) US4 { unsigned short x, y, z, w; };

// Kernel 1: w_bf16 = bf16(mu + eps*sigma); x_bf16 = bf16(x).
// 1M threads, exact trip counts, all loads hoisted for ILP (12 in flight).
// Nontemporal loads on the fp32 weight streams (never re-read) to keep
// wb/xb LLC-resident for the gemm.
__global__ __launch_bounds__(256) void prep_kernel(
    const float* __restrict__ x,
    const float* __restrict__ wmu,
    const float* __restrict__ wsig,
    const float* __restrict__ epsw,
    unsigned short* __restrict__ wb,
    unsigned short* __restrict__ xb)
{
    const size_t tid = (size_t)blockIdx.x * blockDim.x + threadIdx.x;
    const size_t T   = (size_t)1048576;          // 4096 blocks x 256 threads

    const fvec4* wmu4  = (const fvec4*)wmu;
    const fvec4* wsig4 = (const fvec4*)wsig;
    const fvec4* epsw4 = (const fvec4*)epsw;
    US4* wb4 = (US4*)wb;

    fvec4 m[4], s[4], e[4];
    #pragma unroll
    for (int r = 0; r < 4; ++r) {
        const size_t i = tid + (size_t)r * T;    // NW4 = 4T exactly
        m[r] = __builtin_nontemporal_load(wmu4  + i);
        s[r] = __builtin_nontemporal_load(wsig4 + i);
        e[r] = __builtin_nontemporal_load(epsw4 + i);
    }
    #pragma unroll
    for (int r = 0; r < 4; ++r) {
        US4 o;
        o.x = f2bf_bits(fmaf(e[r].x, s[r].x, m[r].x));
        o.y = f2bf_bits(fmaf(e[r].y, s[r].y, m[r].y));
        o.z = f2bf_bits(fmaf(e[r].z, s[r].z, m[r].z));
        o.w = f2bf_bits(fmaf(e[r].w, s[r].w, m[r].w));
        wb4[tid + (size_t)r * T] = o;
    }

    // x: NX4 = T exactly, one fvec4 per thread.
    fvec4 v = __builtin_nontemporal_load((const fvec4*)x + tid);
    US4 o;
    o.x = f2bf_bits(v.x);
    o.y = f2bf_bits(v.y);
    o.z = f2bf_bits(v.z);
    o.w = f2bf_bits(v.w);
    ((US4*)xb)[tid] = o;
}

// Kernel 2: C = A @ B^T + bias, written once (no atomics, no pre-zero).
// A=[M][K] bf16, B=[N][K] bf16. 128x128 tile, grid 256 = 1 block/CU.
// 512 threads = 8 waves: waves 0-3 compute k in [0,2048), waves 4-7
// k in [2048,4096), same four 64x64 quadrants; partials reduced through
// LDS in the epilogue. LDS: 2 x 64 KB double buffer; XOR chunk swizzle
// (applied on the GLOBAL source address, de-swizzled at ds_read) keeps
// both fill and frag reads conflict-free. Single barrier per K-iter with
// prefetch-after-barrier so the global->LDS DMA overlaps MFMA.
__global__ __launch_bounds__(512, 2) void gemm_bt_kernel(
    const unsigned short* __restrict__ A,
    const unsigned short* __restrict__ B,
    const float* __restrict__ bmu,
    const float* __restrict__ bsig,
    const float* __restrict__ ebias,
    float* __restrict__ C)
{
    // Layout (per buffer, 4096 x 16B chunks = 64 KB):
    //   chunks [0,2048): A  = [half][128 rows][8 chunks]
    //   chunks [2048,4096): B, same shape.
    __shared__ unsigned short lds[2 * 32768];

    const int t     = threadIdx.x;
    const int bm0   = blockIdx.y * BM;
    const int bn0   = blockIdx.x * BN;
    const int lane  = t & 63;
    const int wave  = t >> 6;
    const int khalf = wave >> 2;          // 0 or 1: which k-half this wave computes
    const int quadw = wave & 3;
    const int wrow  = (quadw >> 1) * 64;
    const int wcol  = (quadw & 1) * 64;
    const int lm    = lane & 15;
    const int quad  = lane >> 4;

    f32x4_t acc[4][4] = {};

    // Staging: thread t, step s stages global chunk g = t + 512*s into
    // LDS byte offset g*16. Decode: s<4 -> A, s>=4 -> B; half=(s>>1)&1;
    // row=(t>>3)+(s&1)*64; phys chunk j=t&7 -> fetch logical j^(row&7).
    const unsigned short* srcs[8];
    const int rlow = t >> 3;                      // 0..63
    const int jsw  = ((t & 7) ^ (rlow & 7)) * 8;  // swizzled source k-offset (elems)
    #pragma unroll
    for (int s = 0; s < 8; ++s) {
        const int row  = rlow + (s & 1) * 64;
        const int half = (s >> 1) & 1;
        const unsigned short* base = (s < 4)
            ? (A + (size_t)(bm0 + row) * K_IN)
            : (B + (size_t)(bn0 + row) * K_IN);
        srcs[s] = base + half * KPER + jsw;
    }
    char* dst0 = (char*)lds + t * 16;

    // Stage tile 0 into buffer 0.
    #pragma unroll
    for (int s = 0; s < 8; ++s)
        __builtin_amdgcn_global_load_lds(
            (const __attribute__((address_space(1))) void*)(srcs[s]),
            (__attribute__((address_space(3))) void*)(dst0 + s * 8192), 16, 0, 0);

    for (int it = 0; it < KITER; ++it) {
        __syncthreads();  // buf(it&1) ready; prior reads of other buf done

        if (it + 1 < KITER) {
            const int koff = (it + 1) * BK;
            const int nb   = ((it + 1) & 1) * 65536;
            #pragma unroll
            for (int s = 0; s < 8; ++s)
                __builtin_amdgcn_global_load_lds(
                    (const __attribute__((address_space(1))) void*)(srcs[s] + koff),
                    (__attribute__((address_space(3))) void*)(dst0 + nb + s * 8192), 16, 0, 0);
        }

        const unsigned short* Lb = lds + (it & 1) * 32768;
        const unsigned short* Ah = Lb + khalf * 8192;           // A, this wave's half
        const unsigned short* Bh = Lb + 16384 + khalf * 8192;   // B, this wave's half

        #pragma unroll
        for (int kk = 0; kk < 2; ++kk) {          // two 16x16x32 K-steps per BK=64
            const int p = ((kk * 4) + quad) ^ (lm & 7);  // de-swizzled chunk
            bf16x8_t a_frag[4], b_frag[4];
            #pragma unroll
            for (int im = 0; im < 4; im++)
                a_frag[im] = *(const bf16x8_t*)(Ah + ((wrow + im * 16 + lm) * 8 + p) * 8);
            #pragma unroll
            for (int jn = 0; jn < 4; jn++)
                b_frag[jn] = *(const bf16x8_t*)(Bh + ((wcol + jn * 16 + lm) * 8 + p) * 8);
            #pragma unroll
            for (int im = 0; im < 4; im++)
                #pragma unroll
                for (int jn = 0; jn < 4; jn++)
                    acc[im][jn] = __builtin_amdgcn_mfma_f32_16x16x32_bf16(
                        a_frag[im], b_frag[jn], acc[im][jn], 0, 0, 0);
        }
    }

    // Epilogue: reduce the two k-halves through LDS, add bias, store once.
    // Last compute used buffer 1 (bytes [64K,128K)); the 64 KB reduction
    // region reuses buffer 0 — disjoint, so no barrier needed before writes.
    f32x4_t* red = (f32x4_t*)lds;   // 4 regions x 1024 f32x4 (16 KB each)
    if (wave >= 4) {
        #pragma unroll
        for (int im = 0; im < 4; im++)
            #pragma unroll
            for (int jn = 0; jn < 4; jn++)
                red[quadw * 1024 + (im * 4 + jn) * 64 + lane] = acc[im][jn];
    }
    __syncthreads();
    if (wave < 4) {
        #pragma unroll
        for (int jn = 0; jn < 4; jn++) {
            const int gn = bn0 + wcol + jn * 16 + lm;
            const float bias = bmu[gn] + ebias[gn] * bsig[gn];
            #pragma unroll
            for (int im = 0; im < 4; im++) {
                const f32x4_t part = red[quadw * 1024 + (im * 4 + jn) * 64 + lane];
                const int gm0 = bm0 + wrow + im * 16 + quad * 4;
                #pragma unroll
                for (int r = 0; r < 4; r++)
                    C[(size_t)(gm0 + r) * N_OUT + gn] = acc[im][jn][r] + part[r] + bias;
            }
        }
    }
}

// Insurance path if d_ws is too small for the bf16 staging buffers.
__global__ __launch_bounds__(256) void naive_kernel(
    const float* __restrict__ x, const float* __restrict__ wmu,
    const float* __restrict__ wsig, const float* __restrict__ bmu,
    const float* __restrict__ bsig, const float* __restrict__ epsw,
    const float* __restrict__ epsb, float* __restrict__ out)
{
    const int o = blockIdx.x * blockDim.x + threadIdx.x;
    const int b = blockIdx.y;
    const float4* xr = (const float4*)(x + (size_t)b * K_IN);
    const float4* mr = (const float4*)(wmu + (size_t)o * K_IN);
    const float4* sr = (const float4*)(wsig + (size_t)o * K_IN);
    const float4* er = (const float4*)(epsw + (size_t)o * K_IN);
    float s = 0.f;
    for (int k = 0; k < K_IN / 4; k++) {
        float4 xv = xr[k], m = mr[k], sg = sr[k], e = er[k];
        s += xv.x * fmaf(e.x, sg.x, m.x);
        s += xv.y * fmaf(e.y, sg.y, m.y);
        s += xv.z * fmaf(e.z, sg.z, m.z);
        s += xv.w * fmaf(e.w, sg.w, m.w);
    }
    out[(size_t)b * N_OUT + o] = s + bmu[o] + epsb[o] * bsig[o];
}

extern "C" void kernel_launch(void* const* d_in, const int* in_sizes, int n_in,
                              void* d_out, int out_size, void* d_ws, size_t ws_size,
                              hipStream_t stream)
{
    const float* x    = (const float*)d_in[0];
    const float* wmu  = (const float*)d_in[1];
    const float* wsig = (const float*)d_in[2];
    const float* bmu  = (const float*)d_in[3];
    const float* bsig = (const float*)d_in[4];
    const float* epsw = (const float*)d_in[5];
    const float* epsb = (const float*)d_in[6];
    float* out = (float*)d_out;

    const size_t need = ((size_t)N_OUT * K_IN + (size_t)M_BATCH * K_IN) * sizeof(unsigned short);
    if (ws_size >= need) {
        unsigned short* wb = (unsigned short*)d_ws;                  // [N][K] bf16
        unsigned short* xb = wb + (size_t)N_OUT * K_IN;              // [M][K] bf16
        prep_kernel<<<4096, 256, 0, stream>>>(x, wmu, wsig, epsw, wb, xb);
        dim3 grid(N_OUT / BN, M_BATCH / BM);                         // 32 x 8 = 256 blocks
        gemm_bt_kernel<<<grid, 512, 0, stream>>>(xb, wb, bmu, bsig, epsb, out);
    } else {
        dim3 grid(N_OUT / 256, M_BATCH);
        naive_kernel<<<grid, 256, 0, stream>>>(x, wmu, wsig, bmu, bsig, epsw, epsb, out);
    }
}